// Round 12
// baseline (72.071 us; speedup 1.0000x reference)
//
#include <hip/hip_runtime.h>
#include <stdint.h>

typedef __bf16 bf16_t;
typedef __bf16 bf16x8 __attribute__((ext_vector_type(8)));
typedef float f32x4 __attribute__((ext_vector_type(4)));

#define M_DIM 16384
#define N_DIM 1024
#define K_DIM 1024
#define BM 128
#define BN 256
#define BK 32
#define NT (K_DIM / BK)          // 32 K-tiles
#define A_SLOT 8192              // bytes: 128 rows x 64B (bf16)
#define B_SLOT 16384             // bytes: 256 rows x 64B (bf16)
#define B_BASE 16384             // byte offset of B region (after 2 A slots)
// LDS: A[2] (16 KB) + B[2] (32 KB) = 48 KB

// ------- W: binarize (exact reference semantics) + transpose to [N][K] -------
__global__ void bin_transpose_w(const float* __restrict__ W,
                                unsigned short* __restrict__ WbT) {
    __shared__ unsigned short t[64][68];
    int tj = blockIdx.x;                   // n tile
    int ti = blockIdx.y;                   // k tile
    int tid = threadIdx.x;
    int c4 = (tid & 15) * 4;
    int r0 = tid >> 4;
#pragma unroll
    for (int p = 0; p < 4; ++p) {
        int r = r0 + p * 16;
        float4 v = *(const float4*)(W + (size_t)(ti * 64 + r) * N_DIM + tj * 64 + c4);
        // reference: +1 iff (w+1)/2 > 0.5 (round-half-even at exactly 0.5 -> -1)
        t[r][c4 + 0] = ((v.x + 1.0f) * 0.5f > 0.5f) ? 0x3F80 : 0xBF80;
        t[r][c4 + 1] = ((v.y + 1.0f) * 0.5f > 0.5f) ? 0x3F80 : 0xBF80;
        t[r][c4 + 2] = ((v.z + 1.0f) * 0.5f > 0.5f) ? 0x3F80 : 0xBF80;
        t[r][c4 + 3] = ((v.w + 1.0f) * 0.5f > 0.5f) ? 0x3F80 : 0xBF80;
    }
    __syncthreads();
#pragma unroll
    for (int p = 0; p < 4; ++p) {
        int rn = r0 + p * 16;
        ushort4 o;
        o.x = t[c4 + 0][rn];
        o.y = t[c4 + 1][rn];
        o.z = t[c4 + 2][rn];
        o.w = t[c4 + 3][rn];
        *(ushort4*)(WbT + (size_t)(tj * 64 + rn) * K_DIM + ti * 64 + c4) = o;
    }
}

// ------- fused GEMM: A global->reg->cvt->LDS(bf16); B gload_lds; 8 waves -------
__device__ __forceinline__ void gload16(const void* g, const void* l) {
    __builtin_amdgcn_global_load_lds(
        (const __attribute__((address_space(1))) void*)(g),
        (__attribute__((address_space(3))) void*)(l),
        16, 0, 0);
}

__global__ __launch_bounds__(512, 4) void bgemm(const float* __restrict__ X,
                                                const bf16_t* __restrict__ Bt,
                                                const float* __restrict__ bias,
                                                float* __restrict__ C) {
    __shared__ __align__(16) char lds[2 * A_SLOT + 2 * B_SLOT];   // 48 KB

    const int nwg = (M_DIM / BM) * (N_DIM / BN);   // 512, %8==0
    int bid = blockIdx.x;
    int swz = (bid & 7) * (nwg >> 3) + (bid >> 3); // XCD-aware, bijective
    int tile_n = swz & 3;                          // consecutive swz share A panel
    int tile_m = swz >> 2;
    int bm0 = tile_m * BM;
    int bn0 = tile_n * BN;

    int tid = threadIdx.x;
    int w = tid >> 6, l = tid & 63;    // 8 waves: 2(M) x 4(N)
    int wr = w >> 2, wc = w & 3;       // per-wave 64x64 output
    int lr = l & 15, lk = l >> 4;

    // ---- A staging: thread owns row ar (0..127), 16B chunk ac (0..3) ----
    int ar = tid >> 2, ac = tid & 3;
    int aslot = ac ^ ((ar >> 1) & 3);            // R10-proven-zero write swizzle
    const float* asrc = X + (size_t)(bm0 + ar) * K_DIM + ac * 8;
    float4 a_lo, a_hi;                            // staged f32 for next tile
    auto loadA = [&](int t) {                     // 32B contiguous per thread
        const float4* s = (const float4*)(asrc + t * BK);
        a_lo = s[0]; a_hi = s[1];
    };
    auto writeA = [&](int t) {                    // cvt f32->bf16 RNE + ds_write
        bf16x8 v;
        v[0] = (__bf16)a_lo.x; v[1] = (__bf16)a_lo.y;
        v[2] = (__bf16)a_lo.z; v[3] = (__bf16)a_lo.w;
        v[4] = (__bf16)a_hi.x; v[5] = (__bf16)a_hi.y;
        v[6] = (__bf16)a_hi.z; v[7] = (__bf16)a_hi.w;
        *(bf16x8*)(lds + (t & 1) * A_SLOT + ar * 64 + aslot * 16) = v;
    };

    // ---- B staging: gload_lds, linear dest, pre-swizzled source (proven) ----
    int brow = tid >> 2;                       // 0..127 per call (+c*128)
    int bchk = (tid & 3) ^ ((brow >> 1) & 3);
    auto stageB = [&](int t, int c) {
        gload16(Bt + (size_t)(bn0 + c * 128 + brow) * K_DIM + t * BK + bchk * 8,
                lds + B_BASE + (t & 1) * B_SLOT + c * 8192 + tid * 16);
    };

    f32x4 acc[4][4];
#pragma unroll
    for (int m = 0; m < 4; ++m)
#pragma unroll
        for (int n = 0; n < 4; ++n)
            acc[m][n] = (f32x4)(0.0f);

    // ---- prologue: stage tile 0 (A via regs, B via gload), write, barrier ----
    loadA(0);
    stageB(0, 0); stageB(0, 1);
    asm volatile("s_waitcnt vmcnt(0)" ::: "memory");
    writeA(0);
    asm volatile("s_waitcnt lgkmcnt(0)" ::: "memory");
    __builtin_amdgcn_s_barrier();

    for (int t = 0; t < NT; ++t) {
        // ---- issue tile t+1 loads early: A->regs (T14), B->LDS (gload) ----
        if (t + 1 < NT) {
            loadA(t + 1);
            stageB(t + 1, 0); stageB(t + 1, 1);
        }

        const char* Ab = lds + (t & 1) * A_SLOT;
        const char* Bb = lds + B_BASE + (t & 1) * B_SLOT;

        // ---- free-running compute (all single-b128 bf16 reads, proven 0-conflict)
        bf16x8 bfr[4];
#pragma unroll
        for (int n = 0; n < 4; ++n) {
            int br = wc * 64 + n * 16 + lr;
            bfr[n] = *(const bf16x8*)(Bb + br * 64 + ((lk ^ ((br >> 1) & 3)) * 16));
        }
#pragma unroll
        for (int m = 0; m < 4; ++m) {
            int r = wr * 64 + m * 16 + lr;
            bf16x8 afr = *(const bf16x8*)(Ab + r * 64 + ((lk ^ ((r >> 1) & 3)) * 16));
#pragma unroll
            for (int n = 0; n < 4; ++n)
                acc[m][n] = __builtin_amdgcn_mfma_f32_16x16x32_bf16(
                    afr, bfr[n], acc[m][n], 0, 0, 0);
        }

        // ---- boundary: drain loads, write A(t+1), rendezvous ----
        if (t + 1 < NT) {
            asm volatile("s_waitcnt vmcnt(0)" ::: "memory");
            writeA(t + 1);
            asm volatile("s_waitcnt lgkmcnt(0)" ::: "memory");
            __builtin_amdgcn_s_barrier();
        }
    }

    // ---- epilogue: C/D layout col = lane&15, row = (lane>>4)*4 + reg ----
#pragma unroll
    for (int n = 0; n < 4; ++n) {
        int col = bn0 + wc * 64 + n * 16 + lr;
        float bv = bias[col];
#pragma unroll
        for (int m = 0; m < 4; ++m) {
            int row0 = bm0 + wr * 64 + m * 16 + lk * 4;
#pragma unroll
            for (int j = 0; j < 4; ++j)
                C[(size_t)(row0 + j) * N_DIM + col] = acc[m][n][j] + bv;
        }
    }
}

// ---------------- fallback (only if workspace too small) ----------------
__global__ void naive_bin_dense(const float* __restrict__ x,
                                const float* __restrict__ W,
                                const float* __restrict__ b,
                                float* __restrict__ out) {
    int col = blockIdx.x * 256 + threadIdx.x;
    int row = blockIdx.y;
    float acc = 0.0f;
    for (int k = 0; k < K_DIM; ++k) {
        float s = ((W[(size_t)k * N_DIM + col] + 1.0f) * 0.5f > 0.5f) ? 1.0f : -1.0f;
        acc += x[(size_t)row * K_DIM + k] * s;
    }
    out[(size_t)row * N_DIM + col] = acc + b[col];
}

extern "C" void kernel_launch(void* const* d_in, const int* in_sizes, int n_in,
                              void* d_out, int out_size, void* d_ws, size_t ws_size,
                              hipStream_t stream) {
    const float* x = (const float*)d_in[0];
    const float* W = (const float*)d_in[1];
    const float* b = (const float*)d_in[2];
    float* out = (float*)d_out;

    size_t wb_bytes = (size_t)K_DIM * N_DIM * sizeof(unsigned short);

    if (ws_size >= wb_bytes) {
        unsigned short* wbt = (unsigned short*)d_ws;
        hipLaunchKernelGGL(bin_transpose_w, dim3(N_DIM / 64, K_DIM / 64), dim3(256),
                           0, stream, W, wbt);
        hipLaunchKernelGGL(bgemm, dim3((M_DIM / BM) * (N_DIM / BN)), dim3(512), 0, stream,
                           x, (const bf16_t*)wbt, b, out);
    } else {
        hipLaunchKernelGGL(naive_bin_dense, dim3(N_DIM / 256, M_DIM), dim3(256),
                           0, stream, x, W, b, out);
    }
}

// Round 13
// 60.991 us; speedup vs baseline: 1.1817x; 1.1817x over previous
//
#include <hip/hip_runtime.h>
#include <stdint.h>

typedef __bf16 bf16_t;
typedef __bf16 bf16x8 __attribute__((ext_vector_type(8)));
typedef float f32x4 __attribute__((ext_vector_type(4)));

#define M_DIM 16384
#define N_DIM 1024
#define K_DIM 1024
#define BM 128
#define BN 256
#define BK 32
#define NT (K_DIM / BK)          // 32 K-tiles
#define A_SLOT 16384             // bytes: L[128][64] + H[128][64] f32 halves
#define B_SLOT 16384             // bytes: 256 rows x 64B (bf16)
#define B_BASE 32768             // byte offset of B region
// LDS: A[2] + B[2] = 64 KB -> 2 blocks/CU

// ------- W: binarize (exact reference semantics) + transpose to [N][K] -------
__global__ void bin_transpose_w(const float* __restrict__ W,
                                unsigned short* __restrict__ WbT) {
    __shared__ unsigned short t[64][68];
    int tj = blockIdx.x;                   // n tile
    int ti = blockIdx.y;                   // k tile
    int tid = threadIdx.x;
    int c4 = (tid & 15) * 4;
    int r0 = tid >> 4;
#pragma unroll
    for (int p = 0; p < 4; ++p) {
        int r = r0 + p * 16;
        float4 v = *(const float4*)(W + (size_t)(ti * 64 + r) * N_DIM + tj * 64 + c4);
        // reference: +1 iff (w+1)/2 > 0.5 (round-half-even at exactly 0.5 -> -1)
        t[r][c4 + 0] = ((v.x + 1.0f) * 0.5f > 0.5f) ? 0x3F80 : 0xBF80;
        t[r][c4 + 1] = ((v.y + 1.0f) * 0.5f > 0.5f) ? 0x3F80 : 0xBF80;
        t[r][c4 + 2] = ((v.z + 1.0f) * 0.5f > 0.5f) ? 0x3F80 : 0xBF80;
        t[r][c4 + 3] = ((v.w + 1.0f) * 0.5f > 0.5f) ? 0x3F80 : 0xBF80;
    }
    __syncthreads();
#pragma unroll
    for (int p = 0; p < 4; ++p) {
        int rn = r0 + p * 16;
        ushort4 o;
        o.x = t[c4 + 0][rn];
        o.y = t[c4 + 1][rn];
        o.z = t[c4 + 2][rn];
        o.w = t[c4 + 3][rn];
        *(ushort4*)(WbT + (size_t)(tj * 64 + rn) * K_DIM + ti * 64 + c4) = o;
    }
}

// ------- fused cvt-on-read GEMM: C = cvt_bf16(X) * Bt^T + bias -------
__device__ __forceinline__ void gload16(const void* g, const void* l) {
    __builtin_amdgcn_global_load_lds(
        (const __attribute__((address_space(1))) void*)(g),
        (__attribute__((address_space(3))) void*)(l),
        16, 0, 0);
}

__global__ __launch_bounds__(512, 4) void bgemm(const float* __restrict__ X,
                                                const bf16_t* __restrict__ Bt,
                                                const float* __restrict__ bias,
                                                float* __restrict__ C) {
    __shared__ __align__(16) char lds[2 * A_SLOT + 2 * B_SLOT];   // 64 KB

    const int nwg = (M_DIM / BM) * (N_DIM / BN);   // 512, %8==0
    int bid = blockIdx.x;
    int swz = (bid & 7) * (nwg >> 3) + (bid >> 3); // XCD-aware, bijective
    int tile_n = swz & 3;                          // consecutive swz share A panel
    int tile_m = swz >> 2;
    int bm0 = tile_m * BM;
    int bn0 = tile_n * BN;

    int tid = threadIdx.x;
    int w = tid >> 6, l = tid & 63;    // 8 waves: 2(M) x 4(N)
    int wr = w >> 2, wc = w & 3;       // per-wave 64x64 output
    int lr = l & 15, lk = l >> 4;

    // ---- A staging: split-halves layout. Logical 32B chunk c of row r lives
    // as L-half (16B) at Lregion[r][s] and H-half at Hregion[r][s], s = c ^
    // ((r>>1)&3). Each region is 128 rows x 64B = the measured-zero geometry
    // with full lk slot diversity per instruction.
    int arow = tid >> 2;                       // 0..127
    int achk = (tid & 3) ^ ((arow >> 1) & 3);  // logical chunk at slot tid&3
    const float* asrc = X + (size_t)arow * K_DIM + achk * 8;   // + bm0 row later
    auto stageA = [&](int t) {                 // 2 calls: L (+0) and H (+4 floats)
        const float* s0 = asrc + (size_t)bm0 * K_DIM + t * BK;
        gload16(s0,     lds + (t & 1) * A_SLOT + tid * 16);          // L region
        gload16(s0 + 4, lds + (t & 1) * A_SLOT + 8192 + tid * 16);   // H region
    };
    // ---- B staging: gload_lds, linear dest, pre-swizzled source (proven) ----
    int brow = tid >> 2;                       // 0..127 per call (+c*128)
    int bchk = (tid & 3) ^ ((brow >> 1) & 3);
    auto stageB = [&](int t, int c) {
        gload16(Bt + (size_t)(bn0 + c * 128 + brow) * K_DIM + t * BK + bchk * 8,
                lds + B_BASE + (t & 1) * B_SLOT + c * 8192 + tid * 16);
    };

    f32x4 acc[4][4];
#pragma unroll
    for (int m = 0; m < 4; ++m)
#pragma unroll
        for (int n = 0; n < 4; ++n)
            acc[m][n] = (f32x4)(0.0f);

    // ---- prologue: stage tile 0, drain, barrier ----
    stageA(0); stageB(0, 0); stageB(0, 1);
    asm volatile("s_waitcnt vmcnt(0)" ::: "memory");
    __builtin_amdgcn_s_barrier();

    for (int t = 0; t < NT; ++t) {
        // ---- stage tile t+1 early (opposite slot; last read at t-1, retired) ----
        if (t + 1 < NT) {
            stageA(t + 1);
            stageB(t + 1, 0); stageB(t + 1, 1);
        }

        const char* Ab = lds + (t & 1) * A_SLOT;
        const char* Bb = lds + B_BASE + (t & 1) * B_SLOT;

        // ---- B frags: bf16 direct (swizzled read, proven conflict-free) ----
        bf16x8 bfr[4];
#pragma unroll
        for (int n = 0; n < 4; ++n) {
            int br = wc * 64 + n * 16 + lr;
            bfr[n] = *(const bf16x8*)(Bb + br * 64 + ((lk ^ ((br >> 1) & 3)) * 16));
        }
        // ---- A frags: one b128 from L + one from H (both proven-zero pattern),
        //      then 8 in-register RNE casts ----
#pragma unroll
        for (int m = 0; m < 4; ++m) {
            int r = wr * 64 + m * 16 + lr;
            int so = (lk ^ ((r >> 1) & 3)) * 16;
            float4 lo = *(const float4*)(Ab + r * 64 + so);
            float4 hi = *(const float4*)(Ab + 8192 + r * 64 + so);
            bf16x8 afr;
            afr[0] = (__bf16)lo.x; afr[1] = (__bf16)lo.y;
            afr[2] = (__bf16)lo.z; afr[3] = (__bf16)lo.w;
            afr[4] = (__bf16)hi.x; afr[5] = (__bf16)hi.y;
            afr[6] = (__bf16)hi.z; afr[7] = (__bf16)hi.w;
#pragma unroll
            for (int n = 0; n < 4; ++n)
                acc[m][n] = __builtin_amdgcn_mfma_f32_16x16x32_bf16(
                    afr, bfr[n], acc[m][n], 0, 0, 0);
        }

        // ---- boundary: drain staging of t+1, rendezvous ----
        if (t + 1 < NT) {
            asm volatile("s_waitcnt vmcnt(0)" ::: "memory");
            __builtin_amdgcn_s_barrier();
        }
    }

    // ---- epilogue: C/D layout col = lane&15, row = (lane>>4)*4 + reg ----
#pragma unroll
    for (int n = 0; n < 4; ++n) {
        int col = bn0 + wc * 64 + n * 16 + lr;
        float bv = bias[col];
#pragma unroll
        for (int m = 0; m < 4; ++m) {
            int row0 = bm0 + wr * 64 + m * 16 + lk * 4;
#pragma unroll
            for (int j = 0; j < 4; ++j)
                C[(size_t)(row0 + j) * N_DIM + col] = acc[m][n][j] + bv;
        }
    }
}

// ---------------- fallback (only if workspace too small) ----------------
__global__ void naive_bin_dense(const float* __restrict__ x,
                                const float* __restrict__ W,
                                const float* __restrict__ b,
                                float* __restrict__ out) {
    int col = blockIdx.x * 256 + threadIdx.x;
    int row = blockIdx.y;
    float acc = 0.0f;
    for (int k = 0; k < K_DIM; ++k) {
        float s = ((W[(size_t)k * N_DIM + col] + 1.0f) * 0.5f > 0.5f) ? 1.0f : -1.0f;
        acc += x[(size_t)row * K_DIM + k] * s;
    }
    out[(size_t)row * N_DIM + col] = acc + b[col];
}

extern "C" void kernel_launch(void* const* d_in, const int* in_sizes, int n_in,
                              void* d_out, int out_size, void* d_ws, size_t ws_size,
                              hipStream_t stream) {
    const float* x = (const float*)d_in[0];
    const float* W = (const float*)d_in[1];
    const float* b = (const float*)d_in[2];
    float* out = (float*)d_out;

    size_t wb_bytes = (size_t)K_DIM * N_DIM * sizeof(unsigned short);

    if (ws_size >= wb_bytes) {
        unsigned short* wbt = (unsigned short*)d_ws;
        hipLaunchKernelGGL(bin_transpose_w, dim3(N_DIM / 64, K_DIM / 64), dim3(256),
                           0, stream, W, wbt);
        hipLaunchKernelGGL(bgemm, dim3((M_DIM / BM) * (N_DIM / BN)), dim3(512), 0, stream,
                           x, (const bf16_t*)wbt, b, out);
    } else {
        hipLaunchKernelGGL(naive_bin_dense, dim3(N_DIM / 256, M_DIM), dim3(256),
                           0, stream, x, W, b, out);
    }
}

// Round 14
// 49.470 us; speedup vs baseline: 1.4569x; 1.2329x over previous
//
#include <hip/hip_runtime.h>
#include <stdint.h>

typedef __bf16 bf16_t;
typedef __bf16 bf16x8 __attribute__((ext_vector_type(8)));
typedef float f32x4 __attribute__((ext_vector_type(4)));

#define M_DIM 16384
#define N_DIM 1024
#define K_DIM 1024
#define BM 128
#define BN 256
#define BK 32
#define NT (K_DIM / BK)          // 32 K-tiles (even)
#define A_SLOT 8192              // bytes: 128 rows x 64B (bf16)
#define B_SLOT 16384             // bytes: 256 rows x 64B (bf16)
#define B_BASE 16384             // after 2 A slots
// LDS: A[2] + B[2] = 48 KB -> 2 blocks/CU

// ------- W: binarize (exact reference semantics) + transpose to [N][K] -------
__global__ void bin_transpose_w(const float* __restrict__ W,
                                unsigned short* __restrict__ WbT) {
    __shared__ unsigned short t[64][68];
    int tj = blockIdx.x;                   // n tile
    int ti = blockIdx.y;                   // k tile
    int tid = threadIdx.x;
    int c4 = (tid & 15) * 4;
    int r0 = tid >> 4;
#pragma unroll
    for (int p = 0; p < 4; ++p) {
        int r = r0 + p * 16;
        float4 v = *(const float4*)(W + (size_t)(ti * 64 + r) * N_DIM + tj * 64 + c4);
        // reference: +1 iff (w+1)/2 > 0.5 (round-half-even at exactly 0.5 -> -1)
        t[r][c4 + 0] = ((v.x + 1.0f) * 0.5f > 0.5f) ? 0x3F80 : 0xBF80;
        t[r][c4 + 1] = ((v.y + 1.0f) * 0.5f > 0.5f) ? 0x3F80 : 0xBF80;
        t[r][c4 + 2] = ((v.z + 1.0f) * 0.5f > 0.5f) ? 0x3F80 : 0xBF80;
        t[r][c4 + 3] = ((v.w + 1.0f) * 0.5f > 0.5f) ? 0x3F80 : 0xBF80;
    }
    __syncthreads();
#pragma unroll
    for (int p = 0; p < 4; ++p) {
        int rn = r0 + p * 16;
        ushort4 o;
        o.x = t[c4 + 0][rn];
        o.y = t[c4 + 1][rn];
        o.z = t[c4 + 2][rn];
        o.w = t[c4 + 3][rn];
        *(ushort4*)(WbT + (size_t)(tj * 64 + rn) * K_DIM + ti * 64 + c4) = o;
    }
}

// ------- fused GEMM: A global->reg->cvt->LDS(bf16), 2-deep; B gload_lds -------
__device__ __forceinline__ void gload16(const void* g, const void* l) {
    __builtin_amdgcn_global_load_lds(
        (const __attribute__((address_space(1))) void*)(g),
        (__attribute__((address_space(3))) void*)(l),
        16, 0, 0);
}

__global__ __launch_bounds__(512, 4) void bgemm(const float* __restrict__ X,
                                                const bf16_t* __restrict__ Bt,
                                                const float* __restrict__ bias,
                                                float* __restrict__ C) {
    __shared__ __align__(16) char lds[2 * A_SLOT + 2 * B_SLOT];   // 48 KB

    const int nwg = (M_DIM / BM) * (N_DIM / BN);   // 512, %8==0
    int bid = blockIdx.x;
    int swz = (bid & 7) * (nwg >> 3) + (bid >> 3); // XCD-aware, bijective
    int tile_n = swz & 3;                          // consecutive swz share A panel
    int tile_m = swz >> 2;
    int bm0 = tile_m * BM;
    int bn0 = tile_n * BN;

    int tid = threadIdx.x;
    int w = tid >> 6, l = tid & 63;    // 8 waves: 2(M) x 4(N)
    int wr = w >> 2, wc = w & 3;       // per-wave 64x64 output
    int lr = l & 15, lk = l >> 4;

    // ---- A: thread owns row ar (0..127), 32B f32 chunk ac (0..3) ----
    int ar = tid >> 2, ac = tid & 3;
    int aslot = ac ^ ((ar >> 1) & 3);              // proven-zero write swizzle
    const float* asrc = X + (size_t)(bm0 + ar) * K_DIM + ac * 8;

    // ---- B staging: gload_lds, linear dest, pre-swizzled source (proven) ----
    int brow = tid >> 2;
    int bchk = (tid & 3) ^ ((brow >> 1) & 3);
    auto stageB = [&](int t, int c) {
        gload16(Bt + (size_t)(bn0 + c * 128 + brow) * K_DIM + t * BK + bchk * 8,
                lds + B_BASE + (t & 1) * B_SLOT + c * 8192 + tid * 16);
    };
    auto writeA = [&](int t, float4 lo, float4 hi) {   // cvt RNE + 1 ds_write_b128
        bf16x8 v;
        v[0] = (__bf16)lo.x; v[1] = (__bf16)lo.y;
        v[2] = (__bf16)lo.z; v[3] = (__bf16)lo.w;
        v[4] = (__bf16)hi.x; v[5] = (__bf16)hi.y;
        v[6] = (__bf16)hi.z; v[7] = (__bf16)hi.w;
        *(bf16x8*)(lds + (t & 1) * A_SLOT + ar * 64 + aslot * 16) = v;
    };

    f32x4 acc[4][4];
#pragma unroll
    for (int m = 0; m < 4; ++m)
#pragma unroll
        for (int n = 0; n < 4; ++n)
            acc[m][n] = (f32x4)(0.0f);

    // two named A-reg sets: A(k) lives in set k&1 (static indexing, rule #20)
    float4 aL0, aH0, aL1, aH1;

    // ---- prologue ----
    { const float4* s = (const float4*)(asrc + 0 * BK); aL0 = s[0]; aH0 = s[1]; }
    stageB(0, 0); stageB(0, 1);
    { const float4* s = (const float4*)(asrc + 1 * BK); aL1 = s[0]; aH1 = s[1]; }
    writeA(0, aL0, aH0);                       // compiler waits A(0) regs only
    asm volatile("s_waitcnt vmcnt(2)" ::: "memory");   // B(0) resident; A(1) in flight
    asm volatile("s_waitcnt lgkmcnt(0)" ::: "memory"); // ds_write flushed
    __builtin_amdgcn_s_barrier();

    // ---- main loop, unrolled x2 for static A-reg set selection ----
#define TILE_BODY(T, CUR_L, CUR_H, NXT_L, NXT_H)                                  \
    {                                                                             \
        const int t_ = (T);                                                       \
        if (t_ + 1 < NT) { stageB(t_ + 1, 0); stageB(t_ + 1, 1); }                \
        if (t_ + 2 < NT) {                                                        \
            const float4* s = (const float4*)(asrc + (t_ + 2) * BK);              \
            CUR_L = s[0]; CUR_H = s[1];        /* set (t+2)&1 == t&1 */           \
        }                                                                         \
        const char* Ab = lds + (t_ & 1) * A_SLOT;                                 \
        const char* Bb = lds + B_BASE + (t_ & 1) * B_SLOT;                        \
        bf16x8 bfr[4];                                                            \
        _Pragma("unroll") for (int n = 0; n < 4; ++n) {                           \
            int br = wc * 64 + n * 16 + lr;                                       \
            bfr[n] = *(const bf16x8*)(Bb + br * 64 + ((lk ^ ((br >> 1) & 3)) * 16)); \
        }                                                                         \
        _Pragma("unroll") for (int m = 0; m < 4; ++m) {                           \
            int r = wr * 64 + m * 16 + lr;                                        \
            bf16x8 afr = *(const bf16x8*)(Ab + r * 64 + ((lk ^ ((r >> 1) & 3)) * 16)); \
            _Pragma("unroll") for (int n = 0; n < 4; ++n)                         \
                acc[m][n] = __builtin_amdgcn_mfma_f32_16x16x32_bf16(              \
                    afr, bfr[n], acc[m][n], 0, 0, 0);                             \
        }                                                                         \
        if (t_ + 1 < NT) {                                                        \
            writeA(t_ + 1, NXT_L, NXT_H);      /* auto-wait vmcnt(4) for regs */  \
            if (t_ + 2 < NT)                                                      \
                asm volatile("s_waitcnt vmcnt(2)" ::: "memory");  /* B resident */ \
            else                                                                  \
                asm volatile("s_waitcnt vmcnt(0)" ::: "memory");                  \
            asm volatile("s_waitcnt lgkmcnt(0)" ::: "memory");                    \
            __builtin_amdgcn_s_barrier();                                         \
        }                                                                         \
    }

    for (int tt = 0; tt < NT; tt += 2) {
        TILE_BODY(tt,     aL0, aH0, aL1, aH1);   // even t: load->set0, write set1
        TILE_BODY(tt + 1, aL1, aH1, aL0, aH0);   // odd  t: load->set1, write set0
    }
#undef TILE_BODY

    // ---- epilogue: C/D layout col = lane&15, row = (lane>>4)*4 + reg ----
#pragma unroll
    for (int n = 0; n < 4; ++n) {
        int col = bn0 + wc * 64 + n * 16 + lr;
        float bv = bias[col];
#pragma unroll
        for (int m = 0; m < 4; ++m) {
            int row0 = bm0 + wr * 64 + m * 16 + lk * 4;
#pragma unroll
            for (int j = 0; j < 4; ++j)
                C[(size_t)(row0 + j) * N_DIM + col] = acc[m][n][j] + bv;
        }
    }
}

// ---------------- fallback (only if workspace too small) ----------------
__global__ void naive_bin_dense(const float* __restrict__ x,
                                const float* __restrict__ W,
                                const float* __restrict__ b,
                                float* __restrict__ out) {
    int col = blockIdx.x * 256 + threadIdx.x;
    int row = blockIdx.y;
    float acc = 0.0f;
    for (int k = 0; k < K_DIM; ++k) {
        float s = ((W[(size_t)k * N_DIM + col] + 1.0f) * 0.5f > 0.5f) ? 1.0f : -1.0f;
        acc += x[(size_t)row * K_DIM + k] * s;
    }
    out[(size_t)row * N_DIM + col] = acc + b[col];
}

extern "C" void kernel_launch(void* const* d_in, const int* in_sizes, int n_in,
                              void* d_out, int out_size, void* d_ws, size_t ws_size,
                              hipStream_t stream) {
    const float* x = (const float*)d_in[0];
    const float* W = (const float*)d_in[1];
    const float* b = (const float*)d_in[2];
    float* out = (float*)d_out;

    size_t wb_bytes = (size_t)K_DIM * N_DIM * sizeof(unsigned short);

    if (ws_size >= wb_bytes) {
        unsigned short* wbt = (unsigned short*)d_ws;
        hipLaunchKernelGGL(bin_transpose_w, dim3(N_DIM / 64, K_DIM / 64), dim3(256),
                           0, stream, W, wbt);
        hipLaunchKernelGGL(bgemm, dim3((M_DIM / BM) * (N_DIM / BN)), dim3(512), 0, stream,
                           x, (const bf16_t*)wbt, b, out);
    } else {
        hipLaunchKernelGGL(naive_bin_dense, dim3(N_DIM / 256, M_DIM), dim3(256),
                           0, stream, x, W, b, out);
    }
}